// Round 1
// baseline (205.264 us; speedup 1.0000x reference)
//
#include <hip/hip_runtime.h>

#define CC 192
#define WAVES_PER_BLOCK 4

// Map float bits to an unsigned int with the same total order (no NaNs in input).
__device__ __forceinline__ unsigned f2o(float f) {
    unsigned u = __float_as_uint(f);
    return (u & 0x80000000u) ? ~u : (u | 0x80000000u);
}

__device__ __forceinline__ float wave_max(float v) {
#pragma unroll
    for (int o = 32; o > 0; o >>= 1) v = fmaxf(v, __shfl_xor(v, o, 64));
    return v;
}

__device__ __forceinline__ float wave_sum(float v) {
#pragma unroll
    for (int o = 32; o > 0; o >>= 1) v += __shfl_xor(v, o, 64);
    return v;
}

__device__ __forceinline__ unsigned wave_min_u(unsigned v) {
#pragma unroll
    for (int o = 32; o > 0; o >>= 1) {
        unsigned w = (unsigned)__shfl_xor((int)v, o, 64);
        v = (w < v) ? w : v;
    }
    return v;
}

// Exact k-th largest (as ordered uint) among the wave's 192 values
// (a0,a1,a2 per lane). Radix bisection MSB->LSB on #(a >= x) >= k, with an
// early exit: when the count is exactly k, the k-th largest is the min of
// the set {a >= x}. Tie-safe: if counts jump past k (duplicates), the full
// 32-bit bisection converges to the exact bit pattern.
__device__ __forceinline__ unsigned select_kth(unsigned a0, unsigned a1, unsigned a2, int k) {
    unsigned p = 0u;
    for (int b = 31; b >= 0; --b) {
        unsigned x = p | (1u << b);
        unsigned long long m0 = __ballot(a0 >= x);
        unsigned long long m1 = __ballot(a1 >= x);
        unsigned long long m2 = __ballot(a2 >= x);
        int cnt = __popcll(m0) + __popcll(m1) + __popcll(m2);
        if (cnt >= k) {
            p = x;
            if (cnt == k) {
                unsigned c0 = (a0 >= x) ? a0 : 0xFFFFFFFFu;
                unsigned c1 = (a1 >= x) ? a1 : 0xFFFFFFFFu;
                unsigned c2 = (a2 >= x) ? a2 : 0xFFFFFFFFu;
                unsigned c = (c1 < c0) ? c1 : c0;
                c = (c2 < c) ? c2 : c;
                return wave_min_u(c);
            }
        }
    }
    return p;
}

__global__ void __launch_bounds__(WAVES_PER_BLOCK * 64)
sparsify_attn_kernel(const float* __restrict__ A,
                     const float* __restrict__ w1p, const float* __restrict__ w2p,
                     const float* __restrict__ w3p, const float* __restrict__ w4p,
                     float* __restrict__ out, int nrows) {
    const int wid = blockIdx.x * WAVES_PER_BLOCK + (threadIdx.x >> 6);
    if (wid >= nrows) return;  // wave-uniform
    const int lane = threadIdx.x & 63;
    const size_t base = (size_t)wid * CC;

    const float x0 = A[base + lane];
    const float x1 = A[base + lane + 64];
    const float x2 = A[base + lane + 128];
    const unsigned a0 = f2o(x0), a1 = f2o(x1), a2 = f2o(x2);

    const float m = wave_max(fmaxf(x0, fmaxf(x1, x2)));
    const float e0 = __expf(x0 - m);
    const float e1 = __expf(x1 - m);
    const float e2 = __expf(x2 - m);

    const unsigned t1 = select_kth(a0, a1, a2, 96);
    const unsigned t2 = select_kth(a0, a1, a2, 128);
    const unsigned t3 = select_kth(a0, a1, a2, 144);
    const unsigned t4 = select_kth(a0, a1, a2, 153);

    // Z_i = sum of e over {a >= t_i}   (t1 >= t2 >= t3 >= t4 in ordered-uint space)
    float z1 = ((a0 >= t1) ? e0 : 0.f) + ((a1 >= t1) ? e1 : 0.f) + ((a2 >= t1) ? e2 : 0.f);
    float z2 = ((a0 >= t2) ? e0 : 0.f) + ((a1 >= t2) ? e1 : 0.f) + ((a2 >= t2) ? e2 : 0.f);
    float z3 = ((a0 >= t3) ? e0 : 0.f) + ((a1 >= t3) ? e1 : 0.f) + ((a2 >= t3) ? e2 : 0.f);
    float z4 = ((a0 >= t4) ? e0 : 0.f) + ((a1 >= t4) ? e1 : 0.f) + ((a2 >= t4) ? e2 : 0.f);
    z1 = wave_sum(z1);
    z2 = wave_sum(z2);
    z3 = wave_sum(z3);
    z4 = wave_sum(z4);

    const float w1 = *w1p, w2 = *w2p, w3 = *w3p, w4 = *w4p;
    const float c4 = w4 / z4;
    const float c3 = c4 + w3 / z3;
    const float c2 = c3 + w2 / z2;
    const float c1 = c2 + w1 / z1;

    // bucket coefficient: included in every mask whose threshold it clears
    const float o0 = e0 * ((a0 >= t1) ? c1 : (a0 >= t2) ? c2 : (a0 >= t3) ? c3 : (a0 >= t4) ? c4 : 0.f);
    const float o1 = e1 * ((a1 >= t1) ? c1 : (a1 >= t2) ? c2 : (a1 >= t3) ? c3 : (a1 >= t4) ? c4 : 0.f);
    const float o2 = e2 * ((a2 >= t1) ? c1 : (a2 >= t2) ? c2 : (a2 >= t3) ? c3 : (a2 >= t4) ? c4 : 0.f);

    out[base + lane] = o0;
    out[base + lane + 64] = o1;
    out[base + lane + 128] = o2;
}

extern "C" void kernel_launch(void* const* d_in, const int* in_sizes, int n_in,
                              void* d_out, int out_size, void* d_ws, size_t ws_size,
                              hipStream_t stream) {
    const float* attn = (const float*)d_in[0];
    const float* w1 = (const float*)d_in[1];
    const float* w2 = (const float*)d_in[2];
    const float* w3 = (const float*)d_in[3];
    const float* w4 = (const float*)d_in[4];
    float* out = (float*)d_out;

    const int nrows = in_sizes[0] / CC;  // 64*8*192 = 98304
    const int grid = (nrows + WAVES_PER_BLOCK - 1) / WAVES_PER_BLOCK;
    sparsify_attn_kernel<<<grid, WAVES_PER_BLOCK * 64, 0, stream>>>(
        attn, w1, w2, w3, w4, out, nrows);
}